// Round 20
// baseline (136.971 us; speedup 1.0000x reference)
//
#include <hip/hip_runtime.h>

// FeatIterpNFMLP: trilinear grid interp (16^3 x 8ch) + MLP 8->64->64->16 (leaky 0.01)
// Round 20: DIAGNOSTIC build of R18 (best, 27.78 us). NREP=8 repetition of the
// per-group phase (interp -> MLP -> store) with an asm memory clobber per rep
// (rule #17: keeps loads/stores live, output bit-identical). Dispatch ~180 us
// rises above the ~150 us harness fill kernels -> top-5 shows the CURRENT
// structure's VGPR_Count / OccupancyPercent / VALUBusy / MfmaUtil.
// Pre-committed: VGPR<=102 -> occupancy hypothesis dead, declare floor w/ R18;
// VGPR 103-128 -> natural VGPR diet next round (zc/bias constants, pack set).
// Session rules: no d_ws, no forced VGPR caps; XCD swizzle.

typedef __attribute__((ext_vector_type(8)))  short short8;
typedef __attribute__((ext_vector_type(16))) float f32x16;
typedef __attribute__((ext_vector_type(4)))  int   int4v;

#define NREP 8

static __device__ __forceinline__ unsigned cvt_pk_bf16(float lo, float hi) {
    unsigned r;
    asm("v_cvt_pk_bf16_f32 %0, %1, %2" : "=v"(r) : "v"(lo), "v"(hi));
    return r;
}
// v_permlane32_swap_b32: swaps low-32-lane half of a with high-32-lane half of b.
static __device__ __forceinline__ void permswap(unsigned &a, unsigned &b) {
    asm("v_permlane32_swap_b32 %0, %1" : "+v"(a), "+v"(b));
}
static __device__ __forceinline__ short8 as_s8(int4v v) {
    return __builtin_bit_cast(short8, v);
}

// K-axis permutation: B-slot k holds acc value j = jmap(k). (R18 derivation.)
static __device__ __forceinline__ int jmap(int k) {
    const int kt = k >> 4, kk = k & 15, h = kk >> 3, s = kk & 7;
    const int m = s >> 1, e = s & 1;
    const int linear = kt * 4 + m;
    const int rs = linear >> 3, pair = linear & 7;
    const int r = 2 * pair + e;
    return (r & 3) + 8 * (r >> 2) + 4 * h + 32 * rs;
}

// leaky-relu one ct's accum pair, pack IN-LANE in stream order (no cross-lane).
static __device__ __forceinline__ void relu_pack_ct(f32x16 acc[2], int4v bfr[4]) {
    #pragma unroll
    for (int rs = 0; rs < 2; ++rs)
        #pragma unroll
        for (int r = 0; r < 16; ++r) {
            float a = acc[rs][r];
            acc[rs][r] = fmaxf(a, 0.01f * a);
        }
    #pragma unroll
    for (int linear = 0; linear < 16; ++linear) {
        const int rs = linear >> 3, pair = linear & 7;
        const int kt = linear >> 2, m = linear & 3;
        bfr[kt][m] = (int)cvt_pk_bf16(acc[rs][2 * pair], acc[rs][2 * pair + 1]);
    }
}

__global__ __launch_bounds__(512) void featmlp_mfma(
    const int* __restrict__ idx,
    const float* __restrict__ x,
    const float* __restrict__ emb,
    const float* __restrict__ W0, const float* __restrict__ b0,
    const float* __restrict__ W1, const float* __restrict__ b1,
    const float* __restrict__ Wout, const float* __restrict__ bout,
    float* __restrict__ out)
{
    __shared__ int4v frag_lds[17 * 64];        // 17 KB, 16B lane stride

    const int tid  = threadIdx.x;
    const int warp = tid >> 6;                 // 0..7
    const int lane = tid & 63;
    const int half = lane >> 5;
    const int l31  = lane & 31;

    // XCD-chunked swizzle (R14): bijective on [0,1024).
    const int bid = blockIdx.x;
    const int swz = (bid & 7) * 128 + (bid >> 3);
    const int group = swz * 8 + warp;                        // 8192 groups
    const long pbase = (long)group * 64;
    const int  b  = group >> 7;                              // 128 groups / example

    const float* __restrict__ g = emb + ((long)idx[b] << 15);

    // ---- x loads issued first; latency hides under prolog ----
    const long p = pbase + lane;
    const float x0 = x[p * 3 + 0];
    const float x1 = x[p * 3 + 1];
    const float x2 = x[p * 3 + 2];

    // ---- cooperative prolog: 17 fragment families over 8 warps (<=3 each) ----
    for (int fid = warp; fid < 17; fid += 8) {
        int4v f;
        if (fid < 2) {                         // w0f rt=fid; b0 folded at k=8 (identity K)
            const int j = fid * 32 + l31;
            if (half == 0) {
                #pragma unroll
                for (int m = 0; m < 4; ++m)
                    f[m] = (int)cvt_pk_bf16(W0[(2 * m) * 64 + j], W0[(2 * m + 1) * 64 + j]);
            } else {
                f[0] = (int)cvt_pk_bf16(b0[j], 0.0f);       // k=8 -> bias row
                f[1] = 0; f[2] = 0; f[3] = 0;
            }
        } else if (fid < 12) {                 // w1f rt=(fid-2)/5, kt=(fid-2)%5 (jmap'd)
            const int t = fid - 2;
            const int rt = t / 5, kt = t % 5;
            const int j = rt * 32 + l31;
            if (kt < 4) {
                #pragma unroll
                for (int m = 0; m < 4; ++m) {
                    const int k = kt * 16 + half * 8 + 2 * m;
                    f[m] = (int)cvt_pk_bf16(W1[jmap(k) * 64 + j],
                                            W1[jmap(k + 1) * 64 + j]);
                }
            } else {                           // kt=4: k=64 -> b1 row
                f[0] = half ? 0 : (int)cvt_pk_bf16(b1[j], 0.0f);
                f[1] = 0; f[2] = 0; f[3] = 0;
            }
        } else {                               // wof kt=fid-12 (jmap'd; j>=16 clamp)
            const int kt = fid - 12;
            const int jo = l31 < 15 ? l31 : 15;
            if (kt < 4) {
                #pragma unroll
                for (int m = 0; m < 4; ++m) {
                    const int k = kt * 16 + half * 8 + 2 * m;
                    f[m] = (int)cvt_pk_bf16(Wout[jmap(k) * 16 + jo],
                                            Wout[jmap(k + 1) * 16 + jo]);
                }
            } else {                           // kt=4: k=64 -> bout row
                f[0] = half ? 0 : (int)cvt_pk_bf16(bout[jo], 0.0f);
                f[1] = 0; f[2] = 0; f[3] = 0;
            }
        }
        frag_lds[fid * 64 + lane] = f;
    }

    __syncthreads();   // fragments ready (written once; no later writes)

    // ================= DIAGNOSTIC REPEAT: identical work & output each rep ==========
    #pragma unroll 1
    for (int rep = 0; rep < NREP; ++rep) {
        asm volatile("" ::: "memory");   // defeat cross-rep DSE/CSE (rule #17)

        // ---- trilinear interp (no masks/clamps) ----
        const float lx = (x0 + 0.5f) * 15.0f;
        const float ly = (x1 + 0.5f) * 15.0f;
        const float lz = (x2 + 0.5f) * 15.0f;
        const float fx = floorf(lx), fy = floorf(ly), fz = floorf(lz);
        const float wx1 = lx - fx, wy1 = ly - fy, wz1 = lz - fz;
        const float wx0 = 1.0f - wx1, wy0 = 1.0f - wy1, wz0 = 1.0f - wz1;
        const int ix = (int)fx, iy = (int)fy, iz = (int)fz;
        const int vbase = ((iz * 16) + iy) * 16 + ix;

        float feat[8];
        #pragma unroll
        for (int c = 0; c < 8; ++c) feat[c] = 0.0f;
        #pragma unroll
        for (int dz = 0; dz < 2; ++dz) {
            const float wz = dz ? wz1 : wz0;
            #pragma unroll
            for (int dy = 0; dy < 2; ++dy) {
                const float wzy = wz * (dy ? wy1 : wy0);
                #pragma unroll
                for (int dx = 0; dx < 2; ++dx) {
                    const float w = wzy * (dx ? wx1 : wx0);
                    const float4* v = (const float4*)(g + (long)(vbase + dz * 256 + dy * 16 + dx) * 8);
                    const float4 v0 = v[0];
                    const float4 v1 = v[1];
                    feat[0] += w * v0.x; feat[1] += w * v0.y;
                    feat[2] += w * v0.z; feat[3] += w * v0.w;
                    feat[4] += w * v1.x; feat[5] += w * v1.y;
                    feat[6] += w * v1.z; feat[7] += w * v1.w;
                }
            }
        }

        // ---- feat -> layer-0 B-fragments; k=8 row seeded to 1.0 (bias row) ----
        int4v bf0[2];
        #pragma unroll
        for (int m = 0; m < 4; ++m) {
            unsigned a = cvt_pk_bf16(feat[2 * m], feat[2 * m + 1]);
            unsigned z = (m == 0) ? 0x00003f80u : 0u;
            permswap(a, z);
            bf0[0][m] = (int)a;
            bf0[1][m] = (int)z;
        }

        int4v b1x;
        b1x[0] = half ? 0 : 0x00003f80;
        b1x[1] = 0; b1x[2] = 0; b1x[3] = 0;

        f32x16 zc;
        #pragma unroll
        for (int i = 0; i < 16; ++i) zc[i] = 0.0f;

        // ---- ct-sequential MLP ----
        #pragma unroll
        for (int ct = 0; ct < 2; ++ct) {
            f32x16 acc0[2];
            #pragma unroll
            for (int rt = 0; rt < 2; ++rt) {
                const int4v wf = frag_lds[rt * 64 + lane];
                acc0[rt] = __builtin_amdgcn_mfma_f32_32x32x16_bf16(
                    as_s8(wf), as_s8(bf0[ct]), zc, 0, 0, 0);
            }

            int4v b1f[4];
            relu_pack_ct(acc0, b1f);

            f32x16 acc1[2];
            #pragma unroll
            for (int rt = 0; rt < 2; ++rt) {
                f32x16 a = zc;
                #pragma unroll
                for (int kt = 0; kt < 4; ++kt) {
                    const int4v wf = frag_lds[(2 + rt * 5 + kt) * 64 + lane];
                    a = __builtin_amdgcn_mfma_f32_32x32x16_bf16(
                        as_s8(wf), as_s8(b1f[kt]), a, 0, 0, 0);
                }
                const int4v wb = frag_lds[(2 + rt * 5 + 4) * 64 + lane];
                acc1[rt] = __builtin_amdgcn_mfma_f32_32x32x16_bf16(
                    as_s8(wb), as_s8(b1x), a, 0, 0, 0);
            }

            int4v b2f[4];
            relu_pack_ct(acc1, b2f);

            f32x16 a = zc;
            #pragma unroll
            for (int kt = 0; kt < 4; ++kt) {
                const int4v wf = frag_lds[(12 + kt) * 64 + lane];
                a = __builtin_amdgcn_mfma_f32_32x32x16_bf16(
                    as_s8(wf), as_s8(b2f[kt]), a, 0, 0, 0);
            }
            const int4v wb = frag_lds[16 * 64 + lane];
            a = __builtin_amdgcn_mfma_f32_32x32x16_bf16(
                as_s8(wb), as_s8(b1x), a, 0, 0, 0);

            float* o = out + (pbase + ct * 32 + l31) * 16;
            *(float4*)(o + half * 4)     = make_float4(a[0], a[1], a[2], a[3]);
            *(float4*)(o + 8 + half * 4) = make_float4(a[4], a[5], a[6], a[7]);
        }
    }
}

extern "C" void kernel_launch(void* const* d_in, const int* in_sizes, int n_in,
                              void* d_out, int out_size, void* d_ws, size_t ws_size,
                              hipStream_t stream) {
    const int*   idx  = (const int*)  d_in[0];
    const float* x    = (const float*)d_in[1];
    const float* emb  = (const float*)d_in[2];
    const float* W0   = (const float*)d_in[3];
    const float* b0   = (const float*)d_in[4];
    const float* W1   = (const float*)d_in[5];
    const float* b1   = (const float*)d_in[6];
    const float* Wout = (const float*)d_in[7];
    const float* bout = (const float*)d_in[8];
    float* out = (float*)d_out;

    // 8192 groups / 8 per block = 1024 blocks of 512 threads
    featmlp_mfma<<<1024, 512, 0, stream>>>(idx, x, emb, W0, b0, W1, b1,
                                           Wout, bout, out);
}

// Round 21
// 27.856 us; speedup vs baseline: 4.9171x; 4.9171x over previous
//
#include <hip/hip_runtime.h>

// FeatIterpNFMLP: trilinear grid interp (16^3 x 8ch) + MLP 8->64->64->16 (leaky 0.01)
// FINAL (R18 restored, session best: 27.78 us, absmax 2.44e-4).
// Structure: 1024 blocks x 512 thr (8 warps x 1 group of 64 pts), XCD-chunked
// block swizzle (L2-resident grids per XCD), weights+biases as MFMA A-fragments
// in LDS (17 families; biases folded via K-extension rows == 1.0), ct-sequential
// MLP with jmap'd K-permutation so relu->pack is cross-lane-free.
// R20 diagnostic: VGPR=44, warm VALUBusy 52% / MfmaUtil 21%; residual ~13 us is
// L2-hit latency on divergent grid gathers (L1-unfittable working set; LDS
// staging / packing / fission / persistence all measured neutral-or-worse).

typedef __attribute__((ext_vector_type(8)))  short short8;
typedef __attribute__((ext_vector_type(16))) float f32x16;
typedef __attribute__((ext_vector_type(4)))  int   int4v;

static __device__ __forceinline__ unsigned cvt_pk_bf16(float lo, float hi) {
    unsigned r;
    asm("v_cvt_pk_bf16_f32 %0, %1, %2" : "=v"(r) : "v"(lo), "v"(hi));
    return r;
}
// v_permlane32_swap_b32: swaps low-32-lane half of a with high-32-lane half of b.
static __device__ __forceinline__ void permswap(unsigned &a, unsigned &b) {
    asm("v_permlane32_swap_b32 %0, %1" : "+v"(a), "+v"(b));
}
static __device__ __forceinline__ short8 as_s8(int4v v) {
    return __builtin_bit_cast(short8, v);
}

// K-axis permutation: B-slot k holds acc value j = jmap(k).
// Derivation: acc row j = (r&3) + 8*(r>>2) + 4*half; pack stream pair index
// linear = kt*4 + m; rs = linear>>3; pair = linear&7; r = 2*pair + e.
static __device__ __forceinline__ int jmap(int k) {
    const int kt = k >> 4, kk = k & 15, h = kk >> 3, s = kk & 7;
    const int m = s >> 1, e = s & 1;
    const int linear = kt * 4 + m;
    const int rs = linear >> 3, pair = linear & 7;
    const int r = 2 * pair + e;
    return (r & 3) + 8 * (r >> 2) + 4 * h + 32 * rs;
}

// leaky-relu one ct's accum pair, pack IN-LANE in stream order (no cross-lane):
// bfr[kt][m] <- pack(acc[rs][2*pair], acc[rs][2*pair+1]), linear = kt*4+m.
static __device__ __forceinline__ void relu_pack_ct(f32x16 acc[2], int4v bfr[4]) {
    #pragma unroll
    for (int rs = 0; rs < 2; ++rs)
        #pragma unroll
        for (int r = 0; r < 16; ++r) {
            float a = acc[rs][r];
            acc[rs][r] = fmaxf(a, 0.01f * a);
        }
    #pragma unroll
    for (int linear = 0; linear < 16; ++linear) {
        const int rs = linear >> 3, pair = linear & 7;
        const int kt = linear >> 2, m = linear & 3;
        bfr[kt][m] = (int)cvt_pk_bf16(acc[rs][2 * pair], acc[rs][2 * pair + 1]);
    }
}

__global__ __launch_bounds__(512) void featmlp_mfma(
    const int* __restrict__ idx,
    const float* __restrict__ x,
    const float* __restrict__ emb,
    const float* __restrict__ W0, const float* __restrict__ b0,
    const float* __restrict__ W1, const float* __restrict__ b1,
    const float* __restrict__ Wout, const float* __restrict__ bout,
    float* __restrict__ out)
{
    // fid 0-1: w0f[rt] (b0 folded at k=8, identity K order) ;
    // fid 2+rt*5+kt: w1f[rt][kt] kt=0..4 (kt<4 jmap-permuted; kt=4 bias row k=64) ;
    // fid 12+kt: wof[kt] kt=0..4 (same scheme)
    __shared__ int4v frag_lds[17 * 64];        // 17 KB, 16B lane stride

    const int tid  = threadIdx.x;
    const int warp = tid >> 6;                 // 0..7
    const int lane = tid & 63;
    const int half = lane >> 5;
    const int l31  = lane & 31;

    // XCD-chunked swizzle: bijective on [0,1024).
    const int bid = blockIdx.x;
    const int swz = (bid & 7) * 128 + (bid >> 3);
    const int group = swz * 8 + warp;                        // 8192 groups
    const long pbase = (long)group * 64;
    const int  b  = group >> 7;                              // 128 groups / example

    const float* __restrict__ g = emb + ((long)idx[b] << 15);

    // ---- x loads issued first; latency hides under prolog ----
    const long p = pbase + lane;
    const float x0 = x[p * 3 + 0];
    const float x1 = x[p * 3 + 1];
    const float x2 = x[p * 3 + 2];

    // ---- cooperative prolog: 17 fragment families over 8 warps (<=3 each) ----
    // A[row=j2][k]: lane holds row j2 = rt*32 + l31, k = kt*16 + half*8 + 2m+{0,1}
    for (int fid = warp; fid < 17; fid += 8) {
        int4v f;
        if (fid < 2) {                         // w0f rt=fid; b0 folded at k=8 (identity K)
            const int j = fid * 32 + l31;
            if (half == 0) {
                #pragma unroll
                for (int m = 0; m < 4; ++m)
                    f[m] = (int)cvt_pk_bf16(W0[(2 * m) * 64 + j], W0[(2 * m + 1) * 64 + j]);
            } else {
                f[0] = (int)cvt_pk_bf16(b0[j], 0.0f);       // k=8 -> bias row
                f[1] = 0; f[2] = 0; f[3] = 0;
            }
        } else if (fid < 12) {                 // w1f rt=(fid-2)/5, kt=(fid-2)%5 (jmap'd)
            const int t = fid - 2;
            const int rt = t / 5, kt = t % 5;
            const int j = rt * 32 + l31;
            if (kt < 4) {
                #pragma unroll
                for (int m = 0; m < 4; ++m) {
                    const int k = kt * 16 + half * 8 + 2 * m;
                    f[m] = (int)cvt_pk_bf16(W1[jmap(k) * 64 + j],
                                            W1[jmap(k + 1) * 64 + j]);
                }
            } else {                           // kt=4: k=64 -> b1 row
                f[0] = half ? 0 : (int)cvt_pk_bf16(b1[j], 0.0f);
                f[1] = 0; f[2] = 0; f[3] = 0;
            }
        } else {                               // wof kt=fid-12 (jmap'd; rows j>=16 clamp)
            const int kt = fid - 12;
            const int jo = l31 < 15 ? l31 : 15;
            if (kt < 4) {
                #pragma unroll
                for (int m = 0; m < 4; ++m) {
                    const int k = kt * 16 + half * 8 + 2 * m;
                    f[m] = (int)cvt_pk_bf16(Wout[jmap(k) * 16 + jo],
                                            Wout[jmap(k + 1) * 16 + jo]);
                }
            } else {                           // kt=4: k=64 -> bout row
                f[0] = half ? 0 : (int)cvt_pk_bf16(bout[jo], 0.0f);
                f[1] = 0; f[2] = 0; f[3] = 0;
            }
        }
        frag_lds[fid * 64 + lane] = f;
    }

    __syncthreads();   // fragments ready (written once; no later writes)

    // ---- trilinear interp (no masks/clamps: x = -0.5 + k*2^-23 => in-bounds) ----
    const float lx = (x0 + 0.5f) * 15.0f;
    const float ly = (x1 + 0.5f) * 15.0f;
    const float lz = (x2 + 0.5f) * 15.0f;
    const float fx = floorf(lx), fy = floorf(ly), fz = floorf(lz);
    const float wx1 = lx - fx, wy1 = ly - fy, wz1 = lz - fz;
    const float wx0 = 1.0f - wx1, wy0 = 1.0f - wy1, wz0 = 1.0f - wz1;
    const int ix = (int)fx, iy = (int)fy, iz = (int)fz;
    const int vbase = ((iz * 16) + iy) * 16 + ix;

    float feat[8];
    #pragma unroll
    for (int c = 0; c < 8; ++c) feat[c] = 0.0f;
    #pragma unroll
    for (int dz = 0; dz < 2; ++dz) {
        const float wz = dz ? wz1 : wz0;
        #pragma unroll
        for (int dy = 0; dy < 2; ++dy) {
            const float wzy = wz * (dy ? wy1 : wy0);
            #pragma unroll
            for (int dx = 0; dx < 2; ++dx) {
                const float w = wzy * (dx ? wx1 : wx0);
                const float4* v = (const float4*)(g + (long)(vbase + dz * 256 + dy * 16 + dx) * 8);
                const float4 v0 = v[0];
                const float4 v1 = v[1];
                feat[0] += w * v0.x; feat[1] += w * v0.y;
                feat[2] += w * v0.z; feat[3] += w * v0.w;
                feat[4] += w * v1.x; feat[5] += w * v1.y;
                feat[6] += w * v1.z; feat[7] += w * v1.w;
            }
        }
    }

    // ---- feat -> layer-0 B-fragments; k=8 row seeded to 1.0 (bias row) ----
    // (permswap kept here: ct=1 needs upper-lane feats -> real data movement)
    int4v bf0[2];
    #pragma unroll
    for (int m = 0; m < 4; ++m) {
        unsigned a = cvt_pk_bf16(feat[2 * m], feat[2 * m + 1]);
        unsigned z = (m == 0) ? 0x00003f80u : 0u;    // bf16 1.0 at k=8, col-broadcast
        permswap(a, z);
        bf0[0][m] = (int)a;
        bf0[1][m] = (int)z;
    }

    // constant B-fragment for the K=80 bias tile (row 64 == 1.0): lanes<32, m0 low.
    int4v b1x;
    b1x[0] = half ? 0 : 0x00003f80;
    b1x[1] = 0; b1x[2] = 0; b1x[3] = 0;

    f32x16 zc;                                        // shared zero C-operand
    #pragma unroll
    for (int i = 0; i < 16; ++i) zc[i] = 0.0f;

    // ================= ct-sequential MLP (32 points per pass) =================
    #pragma unroll
    for (int ct = 0; ct < 2; ++ct) {
        // ---- layer 0 ----
        f32x16 acc0[2];
        #pragma unroll
        for (int rt = 0; rt < 2; ++rt) {
            const int4v wf = frag_lds[rt * 64 + lane];
            acc0[rt] = __builtin_amdgcn_mfma_f32_32x32x16_bf16(
                as_s8(wf), as_s8(bf0[ct]), zc, 0, 0, 0);
        }

        int4v b1f[4];
        relu_pack_ct(acc0, b1f);        // in-lane pack; W1 fragments are jmap'd

        // ---- layer 1 (K=80: 4 jmap'd data tiles + bias tile) ----
        f32x16 acc1[2];
        #pragma unroll
        for (int rt = 0; rt < 2; ++rt) {
            f32x16 a = zc;
            #pragma unroll
            for (int kt = 0; kt < 4; ++kt) {
                const int4v wf = frag_lds[(2 + rt * 5 + kt) * 64 + lane];
                a = __builtin_amdgcn_mfma_f32_32x32x16_bf16(
                    as_s8(wf), as_s8(b1f[kt]), a, 0, 0, 0);
            }
            const int4v wb = frag_lds[(2 + rt * 5 + 4) * 64 + lane];
            acc1[rt] = __builtin_amdgcn_mfma_f32_32x32x16_bf16(
                as_s8(wb), as_s8(b1x), a, 0, 0, 0);
        }

        int4v b2f[4];
        relu_pack_ct(acc1, b2f);        // in-lane pack; Wout fragments are jmap'd

        // ---- layer 2 (K=80; rows j<16 valid) ----
        f32x16 a = zc;
        #pragma unroll
        for (int kt = 0; kt < 4; ++kt) {
            const int4v wf = frag_lds[(12 + kt) * 64 + lane];
            a = __builtin_amdgcn_mfma_f32_32x32x16_bf16(
                as_s8(wf), as_s8(b2f[kt]), a, 0, 0, 0);
        }
        const int4v wb = frag_lds[16 * 64 + lane];
        a = __builtin_amdgcn_mfma_f32_32x32x16_bf16(
            as_s8(wb), as_s8(b1x), a, 0, 0, 0);

        // j = (r&3) + 8*(r>>2) + 4*half ; point = pbase + ct*32 + l31
        float* o = out + (pbase + ct * 32 + l31) * 16;
        *(float4*)(o + half * 4)     = make_float4(a[0], a[1], a[2], a[3]);
        *(float4*)(o + 8 + half * 4) = make_float4(a[4], a[5], a[6], a[7]);
    }
}

extern "C" void kernel_launch(void* const* d_in, const int* in_sizes, int n_in,
                              void* d_out, int out_size, void* d_ws, size_t ws_size,
                              hipStream_t stream) {
    const int*   idx  = (const int*)  d_in[0];
    const float* x    = (const float*)d_in[1];
    const float* emb  = (const float*)d_in[2];
    const float* W0   = (const float*)d_in[3];
    const float* b0   = (const float*)d_in[4];
    const float* W1   = (const float*)d_in[5];
    const float* b1   = (const float*)d_in[6];
    const float* Wout = (const float*)d_in[7];
    const float* bout = (const float*)d_in[8];
    float* out = (float*)d_out;

    // 8192 groups / 8 per block = 1024 blocks of 512 threads
    featmlp_mfma<<<1024, 512, 0, stream>>>(idx, x, emb, W0, b0, W1, b1,
                                           Wout, bout, out);
}